// Round 2
// baseline (156.163 us; speedup 1.0000x reference)
//
#include <hip/hip_runtime.h>
#include <stdint.h>

// ---------- types & helpers ----------
typedef __attribute__((ext_vector_type(4))) float    f32x4;
typedef __attribute__((ext_vector_type(8))) short    bf16x8;   // 8 bf16 (4 VGPRs) — MFMA operand
typedef __attribute__((ext_vector_type(2))) uint32_t u32x2;

#define MFMA16(a,b,c) __builtin_amdgcn_mfma_f32_16x16x32_bf16((a),(b),(c),0,0,0)

__device__ __forceinline__ uint16_t f2bf(float f){
  uint32_t u = __float_as_uint(f);
  return (uint16_t)((u + 0x7FFFu + ((u >> 16) & 1u)) >> 16);   // RNE
}

__device__ __forceinline__ float fast_exp2(float x){
  float r; asm("v_exp_f32 %0, %1" : "=v"(r) : "v"(x)); return r;
}

// async global->LDS, 16B per lane; LDS dest must be (wave-uniform base + lane*16)
__device__ __forceinline__ void gload16(const uint16_t* g, uint16_t* l){
  __builtin_amdgcn_global_load_lds((const __attribute__((address_space(1))) uint32_t*)g,
                                   (__attribute__((address_space(3))) uint32_t*)l, 16, 0, 0);
}

// ---------- conversion kernels ----------
// x (fp32) -> bf16, 4 elems/thread
__global__ void k_cvt(const float* __restrict__ in, uint16_t* __restrict__ out){
  const size_t i = (size_t)(blockIdx.x*256 + threadIdx.x) * 4;
  const f32x4 v = *(const f32x4*)(in + i);
  uint32_t lo = (uint32_t)f2bf(v[0]) | ((uint32_t)f2bf(v[1])<<16);
  uint32_t hi = (uint32_t)f2bf(v[2]) | ((uint32_t)f2bf(v[3])<<16);
  u32x2 pk = {lo, hi};
  *(u32x2*)(out + i) = pk;
}

// W (K x N fp32) -> Wt (N x K bf16), 64x64 LDS tile transpose (pad 65 -> conflict-free)
__global__ void k_tcvt(const float* __restrict__ in, uint16_t* __restrict__ out, int K, int N){
  __shared__ float tile[64][65];
  const int k0 = blockIdx.y*64, n0 = blockIdx.x*64;
  const int tc = threadIdx.x & 63, tr = threadIdx.x >> 6;
  #pragma unroll
  for (int p=0;p<16;p++){ int r = p*4 + tr; tile[r][tc] = in[(size_t)(k0+r)*N + n0 + tc]; }
  __syncthreads();
  #pragma unroll
  for (int p=0;p<16;p++){ int r = p*4 + tr; out[(size_t)(n0+r)*K + k0 + tc] = f2bf(tile[tc][r]); }
}

// bias_table (4095 x 16) -> bias_t (16 x 4096), pre-scaled by log2(e)
__global__ void k_biast(const float* __restrict__ in, float* __restrict__ out){
  const int i = blockIdx.x*256 + threadIdx.x;
  if (i < 4095*16) out[(i & 15)*4096 + (i >> 4)] = in[i] * 1.4426950408889634f;
}

// ---------- GEMM: C(4096 x N) = A(4096 x 1024) * Bt^T, BM=BN=128, BK=64 ----------
// EPI=0: scatter q (prescaled by dk^-0.5*log2e), k as (b,h,l,d); v transposed as (b,h,d,l)
// EPI=1: fp32 out = acc + proj_b
template<int EPI>
__global__ __launch_bounds__(256, 2) void k_gemm(
    const uint16_t* __restrict__ A, const uint16_t* __restrict__ Bt,
    const float* __restrict__ bias,
    uint16_t* __restrict__ qo, uint16_t* __restrict__ ko, uint16_t* __restrict__ vto,
    float* __restrict__ outf)
{
  __shared__ __align__(16) uint16_t at[128*64];   // [row 128B = 8 chunks], chunk ^= row&7
  __shared__ __align__(16) uint16_t bt[128*64];
  const int tid = threadIdx.x;
  const int lane = tid & 63, w = tid >> 6;
  const int g = lane >> 4, li = lane & 15;
  const int wr = w >> 1, wc = w & 1;
  const int m0 = blockIdx.y * 128, n0 = blockIdx.x * 128;

  f32x4 acc[4][4] = {};

  const int srow = tid >> 3;                       // staging row (+ j*32); row&7 == srow&7
  const int scg  = (tid & 7) ^ (srow & 7);         // inverse-swizzled source chunk

  for (int kt_ = 0; kt_ < 16; kt_++){
    const int kk = kt_*64;
    __syncthreads();                               // prev-iter reads done
    #pragma unroll
    for (int j = 0; j < 4; j++){
      gload16(A  + (size_t)(m0 + j*32 + srow)*1024 + kk + scg*8, at + (j*256+tid)*8);
      gload16(Bt + (size_t)(n0 + j*32 + srow)*1024 + kk + scg*8, bt + (j*256+tid)*8);
    }
    asm volatile("s_waitcnt vmcnt(0)" ::: "memory");
    __syncthreads();

    bf16x8 af[2][4], bfr[2][4];
    #pragma unroll
    for (int mi=0; mi<4; mi++){
      int row = wr*64 + mi*16 + li, sw = row & 7;
      af[0][mi] = *(const bf16x8*)(at + row*64 + ((g     ^ sw)*8));
      af[1][mi] = *(const bf16x8*)(at + row*64 + (((4+g) ^ sw)*8));
    }
    #pragma unroll
    for (int ni=0; ni<4; ni++){
      int row = wc*64 + ni*16 + li, sw = row & 7;
      bfr[0][ni] = *(const bf16x8*)(bt + row*64 + ((g     ^ sw)*8));
      bfr[1][ni] = *(const bf16x8*)(bt + row*64 + (((4+g) ^ sw)*8));
    }
    #pragma unroll
    for (int s=0; s<2; s++)
      #pragma unroll
      for (int mi=0; mi<4; mi++)
        #pragma unroll
        for (int ni=0; ni<4; ni++)
          acc[mi][ni] = MFMA16(af[s][mi], bfr[s][ni], acc[mi][ni]);
  }

  // epilogue: C frag mapping col = lane&15, row = (lane>>4)*4 + reg  [m89-verified]
  if (EPI == 0){
    #pragma unroll
    for (int ni=0; ni<4; ni++){
      const int c = n0 + wc*64 + ni*16 + li;
      const float bv = bias[c];
      const int which = c >> 10, cc = c & 1023;
      const int h = cc >> 6, d = cc & 63;
      #pragma unroll
      for (int mi=0; mi<4; mi++){
        const int trow = m0 + wr*64 + mi*16 + g*4;       // token of reg 0
        const int b_ = trow >> 11, lcl = trow & 2047;
        const f32x4 v4 = acc[mi][ni];
        if (which == 0){
          uint16_t* dst = qo + (((size_t)(b_*16 + h)*2048 + lcl)*64 + d);
          #pragma unroll
          for (int r=0;r<4;r++) dst[(size_t)r*64] = f2bf((v4[r] + bv) * 0.18033688011112042f);
        } else if (which == 1){
          uint16_t* dst = ko + (((size_t)(b_*16 + h)*2048 + lcl)*64 + d);
          #pragma unroll
          for (int r=0;r<4;r++) dst[(size_t)r*64] = f2bf(v4[r] + bv);
        } else {
          uint32_t lo = (uint32_t)f2bf(v4[0]+bv) | ((uint32_t)f2bf(v4[1]+bv)<<16);
          uint32_t hi = (uint32_t)f2bf(v4[2]+bv) | ((uint32_t)f2bf(v4[3]+bv)<<16);
          u32x2 pk = {lo, hi};
          *(u32x2*)(vto + (((size_t)(b_*16 + h)*64 + d)*2048 + lcl)) = pk;  // V^T: 4 tokens contiguous
        }
      }
    }
  } else {
    #pragma unroll
    for (int ni=0; ni<4; ni++){
      const int c = n0 + wc*64 + ni*16 + li;
      const float bv = bias[c];
      #pragma unroll
      for (int mi=0; mi<4; mi++){
        const int trow = m0 + wr*64 + mi*16 + g*4;
        float* dst = outf + (size_t)trow*1024 + c;
        const f32x4 v4 = acc[mi][ni];
        #pragma unroll
        for (int r=0;r<4;r++) dst[(size_t)r*1024] = v4[r] + bv;
      }
    }
  }
}

// ---------- flash attention, S^T orientation ----------
// 4 waves x 16 q-rows (QBLK=64), KVBLK=128, online softmax in exp2 domain.
// S^T = K * Q^T  -> each lane owns one q column; O^T = V^T * P^T via per-wave P LDS round-trip.
__global__ __launch_bounds__(256, 2) void k_attn(
    const uint16_t* __restrict__ qg, const uint16_t* __restrict__ kg,
    const uint16_t* __restrict__ vg, const float* __restrict__ biast,
    uint16_t* __restrict__ outp)
{
  __shared__ __align__(16) uint16_t kt[128*64];    // K tile [kv][dk], 128B rows, swizzled
  __shared__ __align__(16) uint16_t vt[64*128];    // V^T tile [d][kv], 256B rows, swizzled
  __shared__ __align__(16) uint16_t pt[4][16*128]; // per-wave P^T as [q][kv], swizzled
  __shared__ float bl[2112];                       // bias slice: global idx = (kv - q + 2047)
  const int tid = threadIdx.x;
  const int lane = tid & 63, w = tid >> 6;
  const int g = lane >> 4, li = lane & 15;
  const int bh = blockIdx.y, h = bh & 15, b_ = bh >> 4;
  const int qb0 = blockIdx.x * 64;

  // bias index needed: kv_glob - q_glob + 2047, q_glob in [qb0, qb0+63], kv_glob in [0,2047]
  // -> global range [1984 - qb0, 4094 - qb0]; bl[i] = biast[h][1984 - qb0 + i]
  for (int i = tid; i < 2112; i += 256) bl[i] = biast[h*4096 + 1984 - qb0 + i];

  bf16x8 qf[2];   // Q fragment: lane li -> q row, k = 32s + 8g + i (A- and B-layout coincide)
  {
    const uint16_t* qp = qg + ((size_t)bh*2048 + qb0 + w*16 + li)*64 + g*8;
    qf[0] = *(const bf16x8*)(qp);
    qf[1] = *(const bf16x8*)(qp + 32);
  }
  f32x4 o[4] = {};
  float mrun = -__builtin_inff(), lrun = 0.f;
  const uint16_t* kbase = kg + (size_t)bh*(2048*64);
  const uint16_t* vbase = vg + (size_t)bh*(64*2048);
  const int krow = tid >> 3, kcg = (tid & 7)  ^ (krow & 7);
  const int vrow = tid >> 4, vcg = (tid & 15) ^ (vrow & 7);
  const int q_l = w*16 + li;
  uint16_t* pl = &pt[w][0];
  const int swp = li & 7;

  for (int t = 0; t < 16; t++){
    const int kv0 = t * 128;
    __syncthreads();
    #pragma unroll
    for (int j=0;j<4;j++){
      gload16(kbase + (size_t)(kv0 + j*32 + krow)*64 + kcg*8, kt + (j*256+tid)*8);
      gload16(vbase + (size_t)(j*16 + vrow)*2048 + kv0 + vcg*8, vt + (j*256+tid)*8);
    }
    asm volatile("s_waitcnt vmcnt(0)" ::: "memory");
    __syncthreads();

    // S^T(128kv x 16q) = K * Q^T
    f32x4 sa[8];
    #pragma unroll
    for (int mf=0; mf<8; mf++){
      const int row = mf*16 + li, sw = row & 7;
      bf16x8 a0 = *(const bf16x8*)(kt + row*64 + ((g     ^ sw)*8));
      bf16x8 a1 = *(const bf16x8*)(kt + row*64 + (((4+g) ^ sw)*8));
      f32x4 cfr = {};
      cfr = MFMA16(a0, qf[0], cfr);
      cfr = MFMA16(a1, qf[1], cfr);
      sa[mf] = cfr;
    }

    // logits (exp2 domain, bias pre-scaled) + online softmax
    // lane's q = qb0 + q_l; kv = kv0 + mf*16 + g*4 + r
    // bl index = kv_loc - q_l + 63  (kv_loc = kv0 + mf*16 + g*4 + r)
    const int ib0 = kv0 + g*4 + 63 - q_l;
    float tmax = -__builtin_inff();
    #pragma unroll
    for (int mf=0; mf<8; mf++){
      #pragma unroll
      for (int r=0; r<4; r++){
        float vv = sa[mf][r] + bl[ib0 + mf*16 + r];
        sa[mf][r] = vv;
        tmax = fmaxf(tmax, vv);
      }
    }
    tmax = fmaxf(tmax, __shfl_xor(tmax, 16));
    tmax = fmaxf(tmax, __shfl_xor(tmax, 32));
    const float mnew = fmaxf(mrun, tmax);
    const float alpha = fast_exp2(mrun - mnew);    // exp2(-inf)=0 on first tile
    mrun = mnew;
    lrun *= alpha;
    #pragma unroll
    for (int i=0;i<4;i++) o[i] *= alpha;
    float psum = 0.f;
    #pragma unroll
    for (int mf=0; mf<8; mf++){
      float p0 = fast_exp2(sa[mf][0] - mnew);
      float p1 = fast_exp2(sa[mf][1] - mnew);
      float p2 = fast_exp2(sa[mf][2] - mnew);
      float p3 = fast_exp2(sa[mf][3] - mnew);
      psum += (p0+p1)+(p2+p3);
      uint32_t lo = (uint32_t)f2bf(p0) | ((uint32_t)f2bf(p1)<<16);
      uint32_t hi = (uint32_t)f2bf(p2) | ((uint32_t)f2bf(p3)<<16);
      const int ch = (2*mf + (g>>1)) ^ swp;        // kv byte 32mf+8g -> chunk 2mf+(g>>1), half g&1
      u32x2 pk = {lo, hi};
      *(u32x2*)(pl + li*128 + ch*8 + (g&1)*4) = pk;
    }
    psum += __shfl_xor(psum, 16);
    psum += __shfl_xor(psum, 32);
    lrun += psum;

    // O^T(64d x 16q) += V^T * P^T   (same-wave P write->read: compiler inserts lgkmcnt)
    #pragma unroll
    for (int s=0; s<4; s++){
      bf16x8 pb = *(const bf16x8*)(pl + li*128 + (((4*s+g) ^ swp)*8));
      #pragma unroll
      for (int mf=0; mf<4; mf++){
        const int row = mf*16 + li, sw = row & 7;
        bf16x8 av = *(const bf16x8*)(vt + row*128 + (((4*s+g) ^ sw)*8));
        o[mf] = MFMA16(av, pb, o[mf]);
      }
    }
  }

  const float inv = 1.0f / lrun;
  const size_t token = (size_t)b_*2048 + qb0 + w*16 + li;
  #pragma unroll
  for (int mf=0; mf<4; mf++){
    uint32_t lo = (uint32_t)f2bf(o[mf][0]*inv) | ((uint32_t)f2bf(o[mf][1]*inv)<<16);
    uint32_t hi = (uint32_t)f2bf(o[mf][2]*inv) | ((uint32_t)f2bf(o[mf][3]*inv)<<16);
    u32x2 pk = {lo, hi};
    *(u32x2*)(outp + token*1024 + h*64 + mf*16 + g*4) = pk;
  }
}

// ---------- launch ----------
extern "C" void kernel_launch(void* const* d_in, const int* in_sizes, int n_in,
                              void* d_out, int out_size, void* d_ws, size_t ws_size,
                              hipStream_t stream)
{
  const float* x      = (const float*)d_in[0];
  const float* qkv_w  = (const float*)d_in[1];
  const float* qkv_b  = (const float*)d_in[2];
  const float* proj_w = (const float*)d_in[3];
  const float* proj_b = (const float*)d_in[4];
  const float* btab   = (const float*)d_in[5];
  float* out = (float*)d_out;

  char* p = (char*)d_ws;                       // 50,593,792 bytes total
  uint16_t* x_bf    = (uint16_t*)(p);
  uint16_t* qkv_wt  = (uint16_t*)(p + 8388608);
  uint16_t* proj_wt = (uint16_t*)(p + 14680064);
  uint16_t* q_buf   = (uint16_t*)(p + 16777216);   // (b,h,l,d) bf16, prescaled
  uint16_t* k_buf   = (uint16_t*)(p + 25165824);   // (b,h,l,d) bf16
  uint16_t* vt_buf  = (uint16_t*)(p + 33554432);   // (b,h,d,l) bf16
  uint16_t* ao_buf  = (uint16_t*)(p + 41943040);   // attn out (tokens x 1024) bf16
  float*    bias_t  = (float*)   (p + 50331648);   // 16 x 4096 f32, *log2e

  k_cvt  <<<dim3(4096),  dim3(256), 0, stream>>>(x, x_bf);
  k_tcvt <<<dim3(48,16), dim3(256), 0, stream>>>(qkv_w,  qkv_wt,  1024, 3072);
  k_tcvt <<<dim3(16,16), dim3(256), 0, stream>>>(proj_w, proj_wt, 1024, 1024);
  k_biast<<<dim3(256),   dim3(256), 0, stream>>>(btab, bias_t);

  k_gemm<0><<<dim3(24,32), dim3(256), 0, stream>>>(x_bf, qkv_wt, qkv_b, q_buf, k_buf, vt_buf, nullptr);
  k_attn   <<<dim3(32,32), dim3(256), 0, stream>>>(q_buf, k_buf, vt_buf, bias_t, ao_buf);
  k_gemm<1><<<dim3(8,32),  dim3(256), 0, stream>>>(ao_buf, proj_wt, proj_b, nullptr, nullptr, nullptr, out);
}

// Round 3
// 137.465 us; speedup vs baseline: 1.1360x; 1.1360x over previous
//
#include <hip/hip_runtime.h>
#include <stdint.h>

// ---------- types & helpers ----------
typedef __attribute__((ext_vector_type(4))) float    f32x4;
typedef __attribute__((ext_vector_type(8))) short    bf16x8;   // 8 bf16 (4 VGPRs) — MFMA operand
typedef __attribute__((ext_vector_type(2))) uint32_t u32x2;

#define MFMA16(a,b,c) __builtin_amdgcn_mfma_f32_16x16x32_bf16((a),(b),(c),0,0,0)

__device__ __forceinline__ uint16_t f2bf(float f){
  uint32_t u = __float_as_uint(f);
  return (uint16_t)((u + 0x7FFFu + ((u >> 16) & 1u)) >> 16);   // RNE
}

// packed f32x2 -> bf16x2 (RNE), single instruction
__device__ __forceinline__ uint32_t pk_bf16(float lo, float hi){
  uint32_t r; asm("v_cvt_pk_bf16_f32 %0, %1, %2" : "=v"(r) : "v"(lo), "v"(hi)); return r;
}

__device__ __forceinline__ float fast_exp2(float x){
  float r; asm("v_exp_f32 %0, %1" : "=v"(r) : "v"(x)); return r;
}

// async global->LDS, 16B per lane; LDS dest must be (wave-uniform base + lane*16)
__device__ __forceinline__ void gload16(const uint16_t* g, uint16_t* l){
  __builtin_amdgcn_global_load_lds((const __attribute__((address_space(1))) uint32_t*)g,
                                   (__attribute__((address_space(3))) uint32_t*)l, 16, 0, 0);
}

// ---------- conversion kernels ----------
// x (fp32) -> bf16, 4 elems/thread
__global__ void k_cvt(const float* __restrict__ in, uint16_t* __restrict__ out){
  const size_t i = (size_t)(blockIdx.x*256 + threadIdx.x) * 4;
  const f32x4 v = *(const f32x4*)(in + i);
  u32x2 pk = {pk_bf16(v[0], v[1]), pk_bf16(v[2], v[3])};
  *(u32x2*)(out + i) = pk;
}

// W (K x N fp32) -> Wt (N x K bf16), 64x64 LDS tile transpose (pad 65 -> conflict-free)
__global__ void k_tcvt(const float* __restrict__ in, uint16_t* __restrict__ out, int K, int N){
  __shared__ float tile[64][65];
  const int k0 = blockIdx.y*64, n0 = blockIdx.x*64;
  const int tc = threadIdx.x & 63, tr = threadIdx.x >> 6;
  #pragma unroll
  for (int p=0;p<16;p++){ int r = p*4 + tr; tile[r][tc] = in[(size_t)(k0+r)*N + n0 + tc]; }
  __syncthreads();
  #pragma unroll
  for (int p=0;p<16;p++){ int r = p*4 + tr; out[(size_t)(n0+r)*K + k0 + tc] = f2bf(tile[tc][r]); }
}

// bias_table (4095 x 16) -> bias_t (16 x 4096), pre-scaled by log2(e)
__global__ void k_biast(const float* __restrict__ in, float* __restrict__ out){
  const int i = blockIdx.x*256 + threadIdx.x;
  if (i < 4095*16) out[(i & 15)*4096 + (i >> 4)] = in[i] * 1.4426950408889634f;
}

// ---------- GEMM: C(4096 x N) = A(4096 x 1024) * Bt^T, BM=BN=128, BK=64 ----------
// EPI=0: scatter q (prescaled by dk^-0.5*log2e), k as (b,h,l,d); v transposed as (b,h,d,l)
// EPI=1: fp32 out = acc + proj_b
template<int EPI>
__global__ __launch_bounds__(256, 2) void k_gemm(
    const uint16_t* __restrict__ A, const uint16_t* __restrict__ Bt,
    const float* __restrict__ bias,
    uint16_t* __restrict__ qo, uint16_t* __restrict__ ko, uint16_t* __restrict__ vto,
    float* __restrict__ outf)
{
  __shared__ __align__(16) uint16_t at[128*64];   // [row 128B = 8 chunks], chunk ^= row&7
  __shared__ __align__(16) uint16_t bt[128*64];
  const int tid = threadIdx.x;
  const int lane = tid & 63, w = tid >> 6;
  const int g = lane >> 4, li = lane & 15;
  const int wr = w >> 1, wc = w & 1;
  const int m0 = blockIdx.y * 128, n0 = blockIdx.x * 128;

  f32x4 acc[4][4] = {};

  const int srow = tid >> 3;                       // staging row (+ j*32); row&7 == srow&7
  const int scg  = (tid & 7) ^ (srow & 7);         // inverse-swizzled source chunk

  for (int kt_ = 0; kt_ < 16; kt_++){
    const int kk = kt_*64;
    __syncthreads();                               // prev-iter reads done
    #pragma unroll
    for (int j = 0; j < 4; j++){
      gload16(A  + (size_t)(m0 + j*32 + srow)*1024 + kk + scg*8, at + (j*256+tid)*8);
      gload16(Bt + (size_t)(n0 + j*32 + srow)*1024 + kk + scg*8, bt + (j*256+tid)*8);
    }
    asm volatile("s_waitcnt vmcnt(0)" ::: "memory");
    __syncthreads();

    bf16x8 af[2][4], bfr[2][4];
    #pragma unroll
    for (int mi=0; mi<4; mi++){
      int row = wr*64 + mi*16 + li, sw = row & 7;
      af[0][mi] = *(const bf16x8*)(at + row*64 + ((g     ^ sw)*8));
      af[1][mi] = *(const bf16x8*)(at + row*64 + (((4+g) ^ sw)*8));
    }
    #pragma unroll
    for (int ni=0; ni<4; ni++){
      int row = wc*64 + ni*16 + li, sw = row & 7;
      bfr[0][ni] = *(const bf16x8*)(bt + row*64 + ((g     ^ sw)*8));
      bfr[1][ni] = *(const bf16x8*)(bt + row*64 + (((4+g) ^ sw)*8));
    }
    #pragma unroll
    for (int s=0; s<2; s++)
      #pragma unroll
      for (int mi=0; mi<4; mi++)
        #pragma unroll
        for (int ni=0; ni<4; ni++)
          acc[mi][ni] = MFMA16(af[s][mi], bfr[s][ni], acc[mi][ni]);
  }

  // epilogue: C frag mapping col = lane&15, row = (lane>>4)*4 + reg  [m89-verified]
  if (EPI == 0){
    #pragma unroll
    for (int ni=0; ni<4; ni++){
      const int c = n0 + wc*64 + ni*16 + li;
      const float bv = bias[c];
      const int which = c >> 10, cc = c & 1023;
      const int h = cc >> 6, d = cc & 63;
      #pragma unroll
      for (int mi=0; mi<4; mi++){
        const int trow = m0 + wr*64 + mi*16 + g*4;       // token of reg 0
        const int b_ = trow >> 11, lcl = trow & 2047;
        const f32x4 v4 = acc[mi][ni];
        if (which == 0){
          uint16_t* dst = qo + (((size_t)(b_*16 + h)*2048 + lcl)*64 + d);
          #pragma unroll
          for (int r=0;r<4;r++) dst[(size_t)r*64] = f2bf((v4[r] + bv) * 0.18033688011112042f);
        } else if (which == 1){
          uint16_t* dst = ko + (((size_t)(b_*16 + h)*2048 + lcl)*64 + d);
          #pragma unroll
          for (int r=0;r<4;r++) dst[(size_t)r*64] = f2bf(v4[r] + bv);
        } else {
          u32x2 pk = {pk_bf16(v4[0]+bv, v4[1]+bv), pk_bf16(v4[2]+bv, v4[3]+bv)};
          *(u32x2*)(vto + (((size_t)(b_*16 + h)*64 + d)*2048 + lcl)) = pk;  // V^T: 4 tokens contiguous
        }
      }
    }
  } else {
    #pragma unroll
    for (int ni=0; ni<4; ni++){
      const int c = n0 + wc*64 + ni*16 + li;
      const float bv = bias[c];
      #pragma unroll
      for (int mi=0; mi<4; mi++){
        const int trow = m0 + wr*64 + mi*16 + g*4;
        float* dst = outf + (size_t)trow*1024 + c;
        const f32x4 v4 = acc[mi][ni];
        #pragma unroll
        for (int r=0;r<4;r++) dst[(size_t)r*1024] = v4[r] + bv;
      }
    }
  }
}

// ---------- flash attention, S^T orientation, pipelined ----------
// 8 waves x 16 q-rows (QBLK=128), KVBLK=64, double-buffered K/V via global_load_lds,
// counted vmcnt + raw s_barrier (no __syncthreads drain in the loop).
// S^T = K * Q^T -> each lane owns one q column; O^T = V^T * P^T via per-wave P LDS round-trip.
__global__ __launch_bounds__(512, 4) void k_attn(
    const uint16_t* __restrict__ qg, const uint16_t* __restrict__ kg,
    const uint16_t* __restrict__ vg, const float* __restrict__ biast,
    uint16_t* __restrict__ outp)
{
  __shared__ __align__(16) uint16_t kt[2][64*64];  // K tile [kv][dk=64], 128B rows, chunk^=row&7
  __shared__ __align__(16) uint16_t vt[2][64*64];  // V^T tile [d][kv=64], 128B rows, swizzled
  __shared__ __align__(16) uint16_t pt[8][16*64];  // per-wave P^T as [q][kv], swizzled
  __shared__ float bl[2176];                       // bias slice: global idx = (kv - q + 2047)
  const int tid = threadIdx.x;
  const int lane = tid & 63, w = tid >> 6;         // w = 0..7
  const int g = lane >> 4, li = lane & 15;
  const int bh = blockIdx.y, h = bh & 15, b_ = bh >> 4;
  const int qb0 = blockIdx.x * 128;

  // bias idx needed: kv - q + 2047, q in [qb0, qb0+127], kv in [0,2047]
  // -> global range [1920 - qb0, 4094 - qb0] (2175 entries); bl[i] = biast[h][1920 - qb0 + i]
  for (int i = tid; i < 2175; i += 512) bl[i] = biast[h*4096 + 1920 - qb0 + i];

  bf16x8 qf[2];   // Q fragment: lane li -> q row, k = 32s + 8g + i (A- and B-layout coincide)
  {
    const uint16_t* qp = qg + ((size_t)bh*2048 + qb0 + w*16 + li)*64 + g*8;
    qf[0] = *(const bf16x8*)(qp);
    qf[1] = *(const bf16x8*)(qp + 32);
  }
  f32x4 o[4] = {};
  float mrun = -__builtin_inff(), lrun = 0.f;
  const uint16_t* kbase = kg + (size_t)bh*(2048*64);
  const uint16_t* vbase = vg + (size_t)bh*(64*2048);
  const int srow = tid >> 3;                       // staging row, 0..63
  const int scg  = (tid & 7) ^ (srow & 7);         // inverse-swizzled source chunk
  const int q_l = w*16 + li;
  uint16_t* pl = &pt[w][0];
  const int swp = li & 7;

  __syncthreads();   // bl visible to all waves; drains Q/bias loads (vmcnt clean for counting)

  // prologue: stage tile 0 into buffer 0 (2 gloads/thread)
  gload16(kbase + (size_t)srow*64        + scg*8, &kt[0][tid*8]);
  gload16(vbase + (size_t)srow*2048      + scg*8, &vt[0][tid*8]);

  for (int t = 0; t < 32; t++){
    const int cur = t & 1;
    if (t < 31){                                    // prefetch tile t+1 into other buffer
      const int kv1 = (t+1)*64;
      gload16(kbase + (size_t)(kv1 + srow)*64  + scg*8, &kt[cur^1][tid*8]);
      gload16(vbase + (size_t)srow*2048 + kv1  + scg*8, &vt[cur^1][tid*8]);
      asm volatile("s_waitcnt vmcnt(2)" ::: "memory");   // tile-t loads done; t+1 stays in flight
    } else {
      asm volatile("s_waitcnt vmcnt(0)" ::: "memory");
    }
    __builtin_amdgcn_s_barrier();                   // A: tile-t LDS ready for all waves
    const uint16_t* ktc = &kt[cur][0];
    const uint16_t* vtc = &vt[cur][0];
    const int kv0 = t*64;

    // S^T(64kv x 16q) = K * Q^T
    f32x4 sa[4];
    #pragma unroll
    for (int mf=0; mf<4; mf++){
      const int row = mf*16 + li, sw = row & 7;
      bf16x8 a0 = *(const bf16x8*)(ktc + row*64 + ((g     ^ sw)*8));
      bf16x8 a1 = *(const bf16x8*)(ktc + row*64 + (((4+g) ^ sw)*8));
      f32x4 cfr = {};
      cfr = MFMA16(a0, qf[0], cfr);
      cfr = MFMA16(a1, qf[1], cfr);
      sa[mf] = cfr;
    }

    // logits (exp2 domain, bias pre-scaled) + online softmax
    // lane's q = qb0 + q_l; kv_loc = mf*16 + g*4 + r; bl idx = kv0 + kv_loc + 127 - q_l
    const int ib0 = kv0 + g*4 + 127 - q_l;
    float tmax = -__builtin_inff();
    #pragma unroll
    for (int mf=0; mf<4; mf++){
      #pragma unroll
      for (int r=0; r<4; r++){
        float vv = sa[mf][r] + bl[ib0 + mf*16 + r];
        sa[mf][r] = vv;
        tmax = fmaxf(tmax, vv);
      }
    }
    tmax = fmaxf(tmax, __shfl_xor(tmax, 16));
    tmax = fmaxf(tmax, __shfl_xor(tmax, 32));
    const float mnew = fmaxf(mrun, tmax);
    const float alpha = fast_exp2(mrun - mnew);    // exp2(-inf)=0 on first tile
    mrun = mnew;
    lrun *= alpha;
    #pragma unroll
    for (int i=0;i<4;i++) o[i] *= alpha;
    float psum = 0.f;
    #pragma unroll
    for (int mf=0; mf<4; mf++){
      float p0 = fast_exp2(sa[mf][0] - mnew);
      float p1 = fast_exp2(sa[mf][1] - mnew);
      float p2 = fast_exp2(sa[mf][2] - mnew);
      float p3 = fast_exp2(sa[mf][3] - mnew);
      psum += (p0+p1)+(p2+p3);
      const int ch = (2*mf + (g>>1)) ^ swp;        // kv byte 32mf+8g -> chunk 2mf+(g>>1), half g&1
      u32x2 pk = {pk_bf16(p0,p1), pk_bf16(p2,p3)};
      *(u32x2*)(pl + li*64 + ch*8 + (g&1)*4) = pk;
    }
    psum += __shfl_xor(psum, 16);
    psum += __shfl_xor(psum, 32);
    lrun += psum;

    // O^T(64d x 16q) += V^T * P^T   (same-wave P write->read: compiler inserts lgkmcnt)
    #pragma unroll
    for (int s=0; s<2; s++){
      bf16x8 pb = *(const bf16x8*)(pl + li*64 + (((4*s+g) ^ swp)*8));
      #pragma unroll
      for (int mf=0; mf<4; mf++){
        const int row = mf*16 + li, sw = row & 7;
        bf16x8 av = *(const bf16x8*)(vtc + row*64 + (((4*s+g) ^ sw)*8));
        o[mf] = MFMA16(av, pb, o[mf]);
      }
    }
    __builtin_amdgcn_s_barrier();                   // B: all waves done reading buf[cur] before restage
  }

  const float inv = 1.0f / lrun;
  const size_t token = (size_t)b_*2048 + qb0 + w*16 + li;
  #pragma unroll
  for (int mf=0; mf<4; mf++){
    u32x2 pk = {pk_bf16(o[mf][0]*inv, o[mf][1]*inv), pk_bf16(o[mf][2]*inv, o[mf][3]*inv)};
    *(u32x2*)(outp + token*1024 + h*64 + mf*16 + g*4) = pk;
  }
}

// ---------- launch ----------
extern "C" void kernel_launch(void* const* d_in, const int* in_sizes, int n_in,
                              void* d_out, int out_size, void* d_ws, size_t ws_size,
                              hipStream_t stream)
{
  const float* x      = (const float*)d_in[0];
  const float* qkv_w  = (const float*)d_in[1];
  const float* qkv_b  = (const float*)d_in[2];
  const float* proj_w = (const float*)d_in[3];
  const float* proj_b = (const float*)d_in[4];
  const float* btab   = (const float*)d_in[5];
  float* out = (float*)d_out;

  char* p = (char*)d_ws;                       // 50,593,792 bytes total
  uint16_t* x_bf    = (uint16_t*)(p);
  uint16_t* qkv_wt  = (uint16_t*)(p + 8388608);
  uint16_t* proj_wt = (uint16_t*)(p + 14680064);
  uint16_t* q_buf   = (uint16_t*)(p + 16777216);   // (b,h,l,d) bf16, prescaled
  uint16_t* k_buf   = (uint16_t*)(p + 25165824);   // (b,h,l,d) bf16
  uint16_t* vt_buf  = (uint16_t*)(p + 33554432);   // (b,h,d,l) bf16
  uint16_t* ao_buf  = (uint16_t*)(p + 41943040);   // attn out (tokens x 1024) bf16
  float*    bias_t  = (float*)   (p + 50331648);   // 16 x 4096 f32, *log2e

  k_cvt  <<<dim3(4096),  dim3(256), 0, stream>>>(x, x_bf);
  k_tcvt <<<dim3(48,16), dim3(256), 0, stream>>>(qkv_w,  qkv_wt,  1024, 3072);
  k_tcvt <<<dim3(16,16), dim3(256), 0, stream>>>(proj_w, proj_wt, 1024, 1024);
  k_biast<<<dim3(256),   dim3(256), 0, stream>>>(btab, bias_t);

  k_gemm<0><<<dim3(24,32), dim3(256), 0, stream>>>(x_bf, qkv_wt, qkv_b, q_buf, k_buf, vt_buf, nullptr);
  k_attn   <<<dim3(16,32), dim3(512), 0, stream>>>(q_buf, k_buf, vt_buf, bias_t, ao_buf);
  k_gemm<1><<<dim3(8,32),  dim3(256), 0, stream>>>(ao_buf, proj_wt, proj_b, nullptr, nullptr, nullptr, out);
}

// Round 4
// 132.724 us; speedup vs baseline: 1.1766x; 1.0357x over previous
//
#include <hip/hip_runtime.h>
#include <stdint.h>

// ---------- types & helpers ----------
typedef __attribute__((ext_vector_type(4))) float    f32x4;
typedef __attribute__((ext_vector_type(8))) short    bf16x8;   // 8 bf16 (4 VGPRs) — MFMA operand
typedef __attribute__((ext_vector_type(2))) uint32_t u32x2;

#define MFMA16(a,b,c) __builtin_amdgcn_mfma_f32_16x16x32_bf16((a),(b),(c),0,0,0)

__device__ __forceinline__ uint16_t f2bf(float f){
  uint32_t u = __float_as_uint(f);
  return (uint16_t)((u + 0x7FFFu + ((u >> 16) & 1u)) >> 16);   // RNE
}

// packed f32x2 -> bf16x2 (RNE), single instruction
__device__ __forceinline__ uint32_t pk_bf16(float lo, float hi){
  uint32_t r; asm("v_cvt_pk_bf16_f32 %0, %1, %2" : "=v"(r) : "v"(lo), "v"(hi)); return r;
}

__device__ __forceinline__ float fast_exp2(float x){
  float r; asm("v_exp_f32 %0, %1" : "=v"(r) : "v"(x)); return r;
}

// async global->LDS, 16B per lane; LDS dest must be (wave-uniform base + lane*16)
__device__ __forceinline__ void gload16(const uint16_t* g, uint16_t* l){
  __builtin_amdgcn_global_load_lds((const __attribute__((address_space(1))) uint32_t*)g,
                                   (__attribute__((address_space(3))) uint32_t*)l, 16, 0, 0);
}

// ---------- conversion kernels ----------
__global__ void k_cvt(const float* __restrict__ in, uint16_t* __restrict__ out){
  const size_t i = (size_t)(blockIdx.x*256 + threadIdx.x) * 4;
  const f32x4 v = *(const f32x4*)(in + i);
  u32x2 pk = {pk_bf16(v[0], v[1]), pk_bf16(v[2], v[3])};
  *(u32x2*)(out + i) = pk;
}

__global__ void k_tcvt(const float* __restrict__ in, uint16_t* __restrict__ out, int K, int N){
  __shared__ float tile[64][65];
  const int k0 = blockIdx.y*64, n0 = blockIdx.x*64;
  const int tc = threadIdx.x & 63, tr = threadIdx.x >> 6;
  #pragma unroll
  for (int p=0;p<16;p++){ int r = p*4 + tr; tile[r][tc] = in[(size_t)(k0+r)*N + n0 + tc]; }
  __syncthreads();
  #pragma unroll
  for (int p=0;p<16;p++){ int r = p*4 + tr; out[(size_t)(n0+r)*K + k0 + tc] = f2bf(tile[tc][r]); }
}

// bias_table (4095 x 16) -> bias_t (16 x 4096), pre-scaled by log2(e)
__global__ void k_biast(const float* __restrict__ in, float* __restrict__ out){
  const int i = blockIdx.x*256 + threadIdx.x;
  if (i < 4095*16) out[(i & 15)*4096 + (i >> 4)] = in[i] * 1.4426950408889634f;
}

// ---------- GEMM: C(4096 x N) = A(4096 x 1024) * Bt^T, BM=BN=128, BK=64 ----------
template<int EPI>
__global__ __launch_bounds__(256, 2) void k_gemm(
    const uint16_t* __restrict__ A, const uint16_t* __restrict__ Bt,
    const float* __restrict__ bias,
    uint16_t* __restrict__ qo, uint16_t* __restrict__ ko, uint16_t* __restrict__ vto,
    float* __restrict__ outf)
{
  __shared__ __align__(16) uint16_t at[128*64];   // [row 128B = 8 chunks], chunk ^= row&7
  __shared__ __align__(16) uint16_t bt[128*64];
  const int tid = threadIdx.x;
  const int lane = tid & 63, w = tid >> 6;
  const int g = lane >> 4, li = lane & 15;
  const int wr = w >> 1, wc = w & 1;
  const int m0 = blockIdx.y * 128, n0 = blockIdx.x * 128;

  f32x4 acc[4][4] = {};

  const int srow = tid >> 3;
  const int scg  = (tid & 7) ^ (srow & 7);

  for (int kt_ = 0; kt_ < 16; kt_++){
    const int kk = kt_*64;
    __syncthreads();
    #pragma unroll
    for (int j = 0; j < 4; j++){
      gload16(A  + (size_t)(m0 + j*32 + srow)*1024 + kk + scg*8, at + (j*256+tid)*8);
      gload16(Bt + (size_t)(n0 + j*32 + srow)*1024 + kk + scg*8, bt + (j*256+tid)*8);
    }
    asm volatile("s_waitcnt vmcnt(0)" ::: "memory");
    __syncthreads();

    bf16x8 af[2][4], bfr[2][4];
    #pragma unroll
    for (int mi=0; mi<4; mi++){
      int row = wr*64 + mi*16 + li, sw = row & 7;
      af[0][mi] = *(const bf16x8*)(at + row*64 + ((g     ^ sw)*8));
      af[1][mi] = *(const bf16x8*)(at + row*64 + (((4+g) ^ sw)*8));
    }
    #pragma unroll
    for (int ni=0; ni<4; ni++){
      int row = wc*64 + ni*16 + li, sw = row & 7;
      bfr[0][ni] = *(const bf16x8*)(bt + row*64 + ((g     ^ sw)*8));
      bfr[1][ni] = *(const bf16x8*)(bt + row*64 + (((4+g) ^ sw)*8));
    }
    #pragma unroll
    for (int s=0; s<2; s++)
      #pragma unroll
      for (int mi=0; mi<4; mi++)
        #pragma unroll
        for (int ni=0; ni<4; ni++)
          acc[mi][ni] = MFMA16(af[s][mi], bfr[s][ni], acc[mi][ni]);
  }

  if (EPI == 0){
    #pragma unroll
    for (int ni=0; ni<4; ni++){
      const int c = n0 + wc*64 + ni*16 + li;
      const float bv = bias[c];
      const int which = c >> 10, cc = c & 1023;
      const int h = cc >> 6, d = cc & 63;
      #pragma unroll
      for (int mi=0; mi<4; mi++){
        const int trow = m0 + wr*64 + mi*16 + g*4;
        const int b_ = trow >> 11, lcl = trow & 2047;
        const f32x4 v4 = acc[mi][ni];
        if (which == 0){
          uint16_t* dst = qo + (((size_t)(b_*16 + h)*2048 + lcl)*64 + d);
          #pragma unroll
          for (int r=0;r<4;r++) dst[(size_t)r*64] = f2bf((v4[r] + bv) * 0.18033688011112042f);
        } else if (which == 1){
          uint16_t* dst = ko + (((size_t)(b_*16 + h)*2048 + lcl)*64 + d);
          #pragma unroll
          for (int r=0;r<4;r++) dst[(size_t)r*64] = f2bf(v4[r] + bv);
        } else {
          u32x2 pk = {pk_bf16(v4[0]+bv, v4[1]+bv), pk_bf16(v4[2]+bv, v4[3]+bv)};
          *(u32x2*)(vto + (((size_t)(b_*16 + h)*64 + d)*2048 + lcl)) = pk;
        }
      }
    }
  } else {
    #pragma unroll
    for (int ni=0; ni<4; ni++){
      const int c = n0 + wc*64 + ni*16 + li;
      const float bv = bias[c];
      #pragma unroll
      for (int mi=0; mi<4; mi++){
        const int trow = m0 + wr*64 + mi*16 + g*4;
        float* dst = outf + (size_t)trow*1024 + c;
        const f32x4 v4 = acc[mi][ni];
        #pragma unroll
        for (int r=0;r<4;r++) dst[(size_t)r*1024] = v4[r] + bv;
      }
    }
  }
}

// ---------- flash attention: 4 waves x 32 q, KVBLK=64, bias via global, ones-MFMA rowsum ----------
// LDS per wave-tile halved vs 16q/wave (K/V frags serve 2x q). Bias loads ride one
// iteration ahead with the K/V prefetch -> single counted vmcnt(36) per tile.
__device__ __forceinline__ void attn_tile(
    int t, bool last, int tid, int g, int li, int srow, int scg,
    const uint16_t* kbase, const uint16_t* vbase, const float* bb,
    const uint16_t* ktc, uint16_t* ktn, const uint16_t* vtc, uint16_t* vtn, uint16_t* pl,
    const bf16x8 (&qf)[2][2], bf16x8 ones,
    f32x4 (&o)[4][2], f32x4 (&o4)[2], float& mrun0, float& mrun1,
    const float (&bvC)[2][4][4], float (&bvN)[2][4][4])
{
  if (!last){
    const int kv1 = (t+1)*64;
    gload16(kbase + (size_t)(kv1+srow)*64 + scg*8,         ktn + tid*8);
    gload16(kbase + (size_t)(kv1+srow+32)*64 + scg*8,      ktn + 2048 + tid*8);
    gload16(vbase + (size_t)srow*2048 + kv1 + scg*8,       vtn + tid*8);
    gload16(vbase + (size_t)(srow+32)*2048 + kv1 + scg*8,  vtn + 2048 + tid*8);
    #pragma unroll
    for (int c=0;c<2;c++)
      #pragma unroll
      for (int mf=0;mf<4;mf++)
        #pragma unroll
        for (int r=0;r<4;r++)
          bvN[c][mf][r] = bb[kv1 + mf*16 + g*4 + r - c*16 - li];
    // queue (old->new): staged(t)4, bias(t)32, prefetch(t+1)4, bias(t+1)32 = 72
    asm volatile("s_waitcnt vmcnt(36)" ::: "memory");      // retire staged(t)+bias(t)
  } else {
    asm volatile("s_waitcnt vmcnt(0)" ::: "memory");
  }
  __builtin_amdgcn_s_barrier();                            // A: tile t ready

  // S^T(64kv x 32q) = K * Q^T   (K-frags shared across both q col-blocks)
  f32x4 sa[4][2];
  #pragma unroll
  for (int mf=0; mf<4; mf++){
    const int row = mf*16 + li, sw = row & 7;
    bf16x8 a0 = *(const bf16x8*)(ktc + row*64 + ((g     ^ sw)*8));
    bf16x8 a1 = *(const bf16x8*)(ktc + row*64 + (((4+g) ^ sw)*8));
    #pragma unroll
    for (int c=0;c<2;c++){
      f32x4 cfr = {};
      cfr = MFMA16(a0, qf[c][0], cfr);
      cfr = MFMA16(a1, qf[c][1], cfr);
      sa[mf][c] = cfr;
    }
  }

  // bias add + per-q max (lane's q = c-block col li; kv = mf*16+g*4+r)
  float t0 = -__builtin_inff(), t1 = -__builtin_inff();
  #pragma unroll
  for (int mf=0; mf<4; mf++){
    #pragma unroll
    for (int r=0; r<4; r++){
      sa[mf][0][r] += bvC[0][mf][r];
      sa[mf][1][r] += bvC[1][mf][r];
    }
    t0 = fmaxf(t0, fmaxf(fmaxf(sa[mf][0][0], sa[mf][0][1]), fmaxf(sa[mf][0][2], sa[mf][0][3])));
    t1 = fmaxf(t1, fmaxf(fmaxf(sa[mf][1][0], sa[mf][1][1]), fmaxf(sa[mf][1][2], sa[mf][1][3])));
  }
  t0 = fmaxf(t0, __shfl_xor(t0, 16)); t0 = fmaxf(t0, __shfl_xor(t0, 32));
  t1 = fmaxf(t1, __shfl_xor(t1, 16)); t1 = fmaxf(t1, __shfl_xor(t1, 32));

  // defer-max (T13): rescale only when max grew past threshold
  const int ok = (t0 <= mrun0 + 8.f) && (t1 <= mrun1 + 8.f);
  if (!__all(ok)){
    const float mn0 = fmaxf(mrun0, t0), mn1 = fmaxf(mrun1, t1);
    const float a0 = fast_exp2(mrun0 - mn0), a1 = fast_exp2(mrun1 - mn1);
    #pragma unroll
    for (int mf=0; mf<4; mf++){ o[mf][0] *= a0; o[mf][1] *= a1; }
    o4[0] *= a0; o4[1] *= a1;
    mrun0 = mn0; mrun1 = mn1;
  }

  // P = exp2(S - m), pack bf16, store P^T as [32q][64kv] (8B-chunk XOR swizzle, bit0-safe)
  const int swp2 = 2*(li & 7);
  #pragma unroll
  for (int c=0;c<2;c++){
    const float mr = c ? mrun1 : mrun0;
    #pragma unroll
    for (int mf=0; mf<4; mf++){
      float p0 = fast_exp2(sa[mf][c][0] - mr);
      float p1 = fast_exp2(sa[mf][c][1] - mr);
      float p2 = fast_exp2(sa[mf][c][2] - mr);
      float p3 = fast_exp2(sa[mf][c][3] - mr);
      u32x2 pk = {pk_bf16(p0,p1), pk_bf16(p2,p3)};
      *(u32x2*)(pl + (c*16+li)*64 + (((4*mf+g) ^ swp2)*4)) = pk;
    }
  }

  // O^T(64d x 32q) += V^T * P^T ; row-sum via constant ones-row MFMA (replaces psum)
  bf16x8 av[2][4];
  #pragma unroll
  for (int s=0; s<2; s++)
    #pragma unroll
    for (int mf=0; mf<4; mf++){
      const int row = mf*16 + li, sw = row & 7;
      av[s][mf] = *(const bf16x8*)(vtc + row*64 + (((4*s+g) ^ sw)*8));
    }
  #pragma unroll
  for (int c=0;c<2;c++){
    #pragma unroll
    for (int s=0; s<2; s++){
      bf16x8 pb = *(const bf16x8*)(pl + (c*16+li)*64 + (((8*s+2*g) ^ swp2)*4));
      o4[c] = MFMA16(ones, pb, o4[c]);
      #pragma unroll
      for (int mf=0; mf<4; mf++)
        o[mf][c] = MFMA16(av[s][mf], pb, o[mf][c]);
    }
  }
  __builtin_amdgcn_s_barrier();                            // B: done reading tile t
}

__global__ __launch_bounds__(256, 2) void k_attn(
    const uint16_t* __restrict__ qg, const uint16_t* __restrict__ kg,
    const uint16_t* __restrict__ vg, const float* __restrict__ biast,
    uint16_t* __restrict__ outp)
{
  __shared__ __align__(16) uint16_t kt[2][64*64];  // K tile [kv][d], 16B-chunk ^= row&7
  __shared__ __align__(16) uint16_t vt[2][64*64];  // V^T tile [d][kv], same swizzle
  __shared__ __align__(16) uint16_t pt[4][32*64];  // per-wave P^T [32q][64kv]
  const int tid = threadIdx.x;
  const int lane = tid & 63, w = tid >> 6;         // 4 waves
  const int g = lane >> 4, li = lane & 15;
  const int bh = blockIdx.y, h = bh & 15, b_ = bh >> 4;
  const int qb0 = blockIdx.x * 128;
  const int qw = qb0 + w*32;                       // wave's q base (32 rows)

  bf16x8 qf[2][2];
  #pragma unroll
  for (int c=0;c<2;c++){
    const uint16_t* qp = qg + ((size_t)bh*2048 + qw + c*16 + li)*64 + g*8;
    qf[c][0] = *(const bf16x8*)(qp);
    qf[c][1] = *(const bf16x8*)(qp + 32);
  }
  bf16x8 ones = (bf16x8)(short)0;                  // A-frag: row 0 = 1.0, rows 1-15 = 0
  if (li == 0){ const short v = (short)0x3F80; ones = (bf16x8){v,v,v,v,v,v,v,v}; }

  f32x4 o[4][2] = {};
  f32x4 o4[2] = {};
  float mrun0 = -__builtin_inff(), mrun1 = -__builtin_inff();

  const uint16_t* kbase = kg + (size_t)bh*(2048*64);
  const uint16_t* vbase = vg + (size_t)bh*(64*2048);
  const int srow = tid >> 3;                       // 0..31
  const int scg  = (tid & 7) ^ (srow & 7);
  const float* bb = biast + h*4096 + 2047 - qw;    // + kv - (c*16+li)
  uint16_t* pl = &pt[w][0];

  // prologue: stage tile 0, bias tile 0
  gload16(kbase + (size_t)srow*64 + scg*8,         &kt[0][tid*8]);
  gload16(kbase + (size_t)(srow+32)*64 + scg*8,    &kt[0][2048 + tid*8]);
  gload16(vbase + (size_t)srow*2048 + scg*8,       &vt[0][tid*8]);
  gload16(vbase + (size_t)(srow+32)*2048 + scg*8,  &vt[0][2048 + tid*8]);
  float bvA[2][4][4], bvB[2][4][4];
  #pragma unroll
  for (int c=0;c<2;c++)
    #pragma unroll
    for (int mf=0;mf<4;mf++)
      #pragma unroll
      for (int r=0;r<4;r++)
        bvA[c][mf][r] = bb[mf*16 + g*4 + r - c*16 - li];

  for (int tt = 0; tt < 32; tt += 2){
    attn_tile(tt,   false,    tid, g, li, srow, scg, kbase, vbase, bb,
              &kt[0][0], &kt[1][0], &vt[0][0], &vt[1][0], pl,
              qf, ones, o, o4, mrun0, mrun1, bvA, bvB);
    attn_tile(tt+1, tt == 30, tid, g, li, srow, scg, kbase, vbase, bb,
              &kt[1][0], &kt[0][0], &vt[1][0], &vt[0][0], pl,
              qf, ones, o, o4, mrun0, mrun1, bvB, bvA);
  }

  // row sums live in o4[c] reg 0 of lane-group g=0; broadcast to all g
  const float ls0 = __shfl(o4[0][0], li);
  const float ls1 = __shfl(o4[1][0], li);
  const float inv0 = 1.0f / ls0, inv1 = 1.0f / ls1;
  #pragma unroll
  for (int c=0;c<2;c++){
    const float inv = c ? inv1 : inv0;
    const size_t token = (size_t)b_*2048 + qw + c*16 + li;
    #pragma unroll
    for (int mf=0; mf<4; mf++){
      u32x2 pk = {pk_bf16(o[mf][c][0]*inv, o[mf][c][1]*inv),
                  pk_bf16(o[mf][c][2]*inv, o[mf][c][3]*inv)};
      *(u32x2*)(outp + token*1024 + h*64 + mf*16 + g*4) = pk;
    }
  }
}

// ---------- launch ----------
extern "C" void kernel_launch(void* const* d_in, const int* in_sizes, int n_in,
                              void* d_out, int out_size, void* d_ws, size_t ws_size,
                              hipStream_t stream)
{
  const float* x      = (const float*)d_in[0];
  const float* qkv_w  = (const float*)d_in[1];
  const float* qkv_b  = (const float*)d_in[2];
  const float* proj_w = (const float*)d_in[3];
  const float* proj_b = (const float*)d_in[4];
  const float* btab   = (const float*)d_in[5];
  float* out = (float*)d_out;

  char* p = (char*)d_ws;
  uint16_t* x_bf    = (uint16_t*)(p);
  uint16_t* qkv_wt  = (uint16_t*)(p + 8388608);
  uint16_t* proj_wt = (uint16_t*)(p + 14680064);
  uint16_t* q_buf   = (uint16_t*)(p + 16777216);   // (b,h,l,d) bf16, prescaled
  uint16_t* k_buf   = (uint16_t*)(p + 25165824);   // (b,h,l,d) bf16
  uint16_t* vt_buf  = (uint16_t*)(p + 33554432);   // (b,h,d,l) bf16
  uint16_t* ao_buf  = (uint16_t*)(p + 41943040);   // attn out (tokens x 1024) bf16
  float*    bias_t  = (float*)   (p + 50331648);   // 16 x 4096 f32, *log2e

  k_cvt  <<<dim3(4096),  dim3(256), 0, stream>>>(x, x_bf);
  k_tcvt <<<dim3(48,16), dim3(256), 0, stream>>>(qkv_w,  qkv_wt,  1024, 3072);
  k_tcvt <<<dim3(16,16), dim3(256), 0, stream>>>(proj_w, proj_wt, 1024, 1024);
  k_biast<<<dim3(256),   dim3(256), 0, stream>>>(btab, bias_t);

  k_gemm<0><<<dim3(24,32), dim3(256), 0, stream>>>(x_bf, qkv_wt, qkv_b, q_buf, k_buf, vt_buf, nullptr);
  k_attn   <<<dim3(16,32), dim3(256), 0, stream>>>(q_buf, k_buf, vt_buf, bias_t, ao_buf);
  k_gemm<1><<<dim3(8,32),  dim3(256), 0, stream>>>(ao_buf, proj_wt, proj_b, nullptr, nullptr, nullptr, out);
}

// Round 5
// 128.352 us; speedup vs baseline: 1.2167x; 1.0341x over previous
//
#include <hip/hip_runtime.h>
#include <stdint.h>

// ---------- types & helpers ----------
typedef __attribute__((ext_vector_type(4))) float    f32x4;
typedef f32x4 __attribute__((aligned(4)))   f32x4u;  // 4B-aligned vector load (global allows it)
typedef __attribute__((ext_vector_type(8))) short    bf16x8;   // 8 bf16 (4 VGPRs) — MFMA operand
typedef __attribute__((ext_vector_type(2))) uint32_t u32x2;

#define MFMA16(a,b,c) __builtin_amdgcn_mfma_f32_16x16x32_bf16((a),(b),(c),0,0,0)

__device__ __forceinline__ uint16_t f2bf(float f){
  uint32_t u = __float_as_uint(f);
  return (uint16_t)((u + 0x7FFFu + ((u >> 16) & 1u)) >> 16);   // RNE
}

// packed f32x2 -> bf16x2 (RNE), single instruction
__device__ __forceinline__ uint32_t pk_bf16(float lo, float hi){
  uint32_t r; asm("v_cvt_pk_bf16_f32 %0, %1, %2" : "=v"(r) : "v"(lo), "v"(hi)); return r;
}

__device__ __forceinline__ float fast_exp2(float x){
  float r; asm("v_exp_f32 %0, %1" : "=v"(r) : "v"(x)); return r;
}

// async global->LDS, 16B per lane; LDS dest must be (wave-uniform base + lane*16)
__device__ __forceinline__ void gload16(const uint16_t* g, uint16_t* l){
  __builtin_amdgcn_global_load_lds((const __attribute__((address_space(1))) uint32_t*)g,
                                   (__attribute__((address_space(3))) uint32_t*)l, 16, 0, 0);
}

// ---------- conversion kernels ----------
__global__ void k_cvt(const float* __restrict__ in, uint16_t* __restrict__ out){
  const size_t i = (size_t)(blockIdx.x*256 + threadIdx.x) * 4;
  const f32x4 v = *(const f32x4*)(in + i);
  u32x2 pk = {pk_bf16(v[0], v[1]), pk_bf16(v[2], v[3])};
  *(u32x2*)(out + i) = pk;
}

__global__ void k_tcvt(const float* __restrict__ in, uint16_t* __restrict__ out, int K, int N){
  __shared__ float tile[64][65];
  const int k0 = blockIdx.y*64, n0 = blockIdx.x*64;
  const int tc = threadIdx.x & 63, tr = threadIdx.x >> 6;
  #pragma unroll
  for (int p=0;p<16;p++){ int r = p*4 + tr; tile[r][tc] = in[(size_t)(k0+r)*N + n0 + tc]; }
  __syncthreads();
  #pragma unroll
  for (int p=0;p<16;p++){ int r = p*4 + tr; out[(size_t)(n0+r)*K + k0 + tc] = f2bf(tile[tc][r]); }
}

// bias_table (4095 x 16) -> bias_t (16 x 4096), pre-scaled by log2(e)
__global__ void k_biast(const float* __restrict__ in, float* __restrict__ out){
  const int i = blockIdx.x*256 + threadIdx.x;
  if (i < 4095*16) out[(i & 15)*4096 + (i >> 4)] = in[i] * 1.4426950408889634f;
}

// ---------- GEMM: C(4096 x N) = A(4096 x 1024) * Bt^T, BM=BN=128, BK=64 ----------
template<int EPI>
__global__ __launch_bounds__(256, 2) void k_gemm(
    const uint16_t* __restrict__ A, const uint16_t* __restrict__ Bt,
    const float* __restrict__ bias,
    uint16_t* __restrict__ qo, uint16_t* __restrict__ ko, uint16_t* __restrict__ vto,
    float* __restrict__ outf)
{
  __shared__ __align__(16) uint16_t at[128*64];   // [row 128B = 8 chunks], chunk ^= row&7
  __shared__ __align__(16) uint16_t bt[128*64];
  const int tid = threadIdx.x;
  const int lane = tid & 63, w = tid >> 6;
  const int g = lane >> 4, li = lane & 15;
  const int wr = w >> 1, wc = w & 1;
  const int m0 = blockIdx.y * 128, n0 = blockIdx.x * 128;

  f32x4 acc[4][4] = {};

  const int srow = tid >> 3;
  const int scg  = (tid & 7) ^ (srow & 7);

  for (int kt_ = 0; kt_ < 16; kt_++){
    const int kk = kt_*64;
    __syncthreads();
    #pragma unroll
    for (int j = 0; j < 4; j++){
      gload16(A  + (size_t)(m0 + j*32 + srow)*1024 + kk + scg*8, at + (j*256+tid)*8);
      gload16(Bt + (size_t)(n0 + j*32 + srow)*1024 + kk + scg*8, bt + (j*256+tid)*8);
    }
    asm volatile("s_waitcnt vmcnt(0)" ::: "memory");
    __syncthreads();

    bf16x8 af[2][4], bfr[2][4];
    #pragma unroll
    for (int mi=0; mi<4; mi++){
      int row = wr*64 + mi*16 + li, sw = row & 7;
      af[0][mi] = *(const bf16x8*)(at + row*64 + ((g     ^ sw)*8));
      af[1][mi] = *(const bf16x8*)(at + row*64 + (((4+g) ^ sw)*8));
    }
    #pragma unroll
    for (int ni=0; ni<4; ni++){
      int row = wc*64 + ni*16 + li, sw = row & 7;
      bfr[0][ni] = *(const bf16x8*)(bt + row*64 + ((g     ^ sw)*8));
      bfr[1][ni] = *(const bf16x8*)(bt + row*64 + (((4+g) ^ sw)*8));
    }
    #pragma unroll
    for (int s=0; s<2; s++)
      #pragma unroll
      for (int mi=0; mi<4; mi++)
        #pragma unroll
        for (int ni=0; ni<4; ni++)
          acc[mi][ni] = MFMA16(af[s][mi], bfr[s][ni], acc[mi][ni]);
  }

  if (EPI == 0){
    #pragma unroll
    for (int ni=0; ni<4; ni++){
      const int c = n0 + wc*64 + ni*16 + li;
      const float bv = bias[c];
      const int which = c >> 10, cc = c & 1023;
      const int h = cc >> 6, d = cc & 63;
      #pragma unroll
      for (int mi=0; mi<4; mi++){
        const int trow = m0 + wr*64 + mi*16 + g*4;
        const int b_ = trow >> 11, lcl = trow & 2047;
        const f32x4 v4 = acc[mi][ni];
        if (which == 0){
          uint16_t* dst = qo + (((size_t)(b_*16 + h)*2048 + lcl)*64 + d);
          #pragma unroll
          for (int r=0;r<4;r++) dst[(size_t)r*64] = f2bf((v4[r] + bv) * 0.18033688011112042f);
        } else if (which == 1){
          uint16_t* dst = ko + (((size_t)(b_*16 + h)*2048 + lcl)*64 + d);
          #pragma unroll
          for (int r=0;r<4;r++) dst[(size_t)r*64] = f2bf(v4[r] + bv);
        } else {
          u32x2 pk = {pk_bf16(v4[0]+bv, v4[1]+bv), pk_bf16(v4[2]+bv, v4[3]+bv)};
          *(u32x2*)(vto + (((size_t)(b_*16 + h)*64 + d)*2048 + lcl)) = pk;
        }
      }
    }
  } else {
    #pragma unroll
    for (int ni=0; ni<4; ni++){
      const int c = n0 + wc*64 + ni*16 + li;
      const float bv = bias[c];
      #pragma unroll
      for (int mi=0; mi<4; mi++){
        const int trow = m0 + wr*64 + mi*16 + g*4;
        float* dst = outf + (size_t)trow*1024 + c;
        const f32x4 v4 = acc[mi][ni];
        #pragma unroll
        for (int r=0;r<4;r++) dst[(size_t)r*1024] = v4[r] + bv;
      }
    }
  }
}

// ---------- flash attention: 4 waves x 32 q, KVBLK=64 ----------
// Bias via vectorized global loads (8x f32x4/tile), shuffle-free defer-max common path,
// ones-row MFMA rowsum, s_setprio around MFMA clusters, counted vmcnt double-buffer.
__device__ __forceinline__ void attn_tile(
    int t, bool last, int tid, int g, int li, int srow, int scg,
    const uint16_t* kbase, const uint16_t* vbase, const float* bb,
    const uint16_t* ktc, uint16_t* ktn, const uint16_t* vtc, uint16_t* vtn, uint16_t* pl,
    const bf16x8 (&qf)[2][2], bf16x8 ones,
    f32x4 (&o)[4][2], f32x4 (&o4)[2], float& mrun0, float& mrun1,
    const f32x4 (&bvC)[2][4], f32x4 (&bvN)[2][4])
{
  if (!last){
    const int kv1 = (t+1)*64;
    gload16(kbase + (size_t)(kv1+srow)*64 + scg*8,         ktn + tid*8);
    gload16(kbase + (size_t)(kv1+srow+32)*64 + scg*8,      ktn + 2048 + tid*8);
    gload16(vbase + (size_t)srow*2048 + kv1 + scg*8,       vtn + tid*8);
    gload16(vbase + (size_t)(srow+32)*2048 + kv1 + scg*8,  vtn + 2048 + tid*8);
    #pragma unroll
    for (int c=0;c<2;c++)
      #pragma unroll
      for (int mf=0;mf<4;mf++)
        bvN[c][mf] = *(const f32x4u*)(bb + kv1 + mf*16 + g*4 - c*16 - li);
    // queue (old->new): staged(t)4 + bias(t)8, prefetch(t+1)4 + bias(t+1)8 = 24
    asm volatile("s_waitcnt vmcnt(12)" ::: "memory");      // retire staged(t)+bias(t)
  } else {
    asm volatile("s_waitcnt vmcnt(0)" ::: "memory");
  }
  __builtin_amdgcn_s_barrier();                            // A: tile t ready

  // S^T(64kv x 32q) = K * Q^T   (K-frags shared across both q col-blocks)
  f32x4 sa[4][2];
  __builtin_amdgcn_s_setprio(1);
  #pragma unroll
  for (int mf=0; mf<4; mf++){
    const int row = mf*16 + li, sw = row & 7;
    bf16x8 a0 = *(const bf16x8*)(ktc + row*64 + ((g     ^ sw)*8));
    bf16x8 a1 = *(const bf16x8*)(ktc + row*64 + (((4+g) ^ sw)*8));
    #pragma unroll
    for (int c=0;c<2;c++){
      f32x4 cfr = {};
      cfr = MFMA16(a0, qf[c][0], cfr);
      cfr = MFMA16(a1, qf[c][1], cfr);
      sa[mf][c] = cfr;
    }
  }
  __builtin_amdgcn_s_setprio(0);

  // bias add + lane-local max (q = c*16+li; kv = mf*16+g*4+r)
  float t0 = -__builtin_inff(), t1 = -__builtin_inff();
  #pragma unroll
  for (int mf=0; mf<4; mf++){
    sa[mf][0] += bvC[0][mf];
    sa[mf][1] += bvC[1][mf];
    #pragma unroll
    for (int r=0; r<4; r++){
      t0 = fmaxf(t0, sa[mf][0][r]);
      t1 = fmaxf(t1, sa[mf][1][r]);
    }
  }

  // defer-max (T13): common path has NO cross-lane ops. mrun is q-uniform; the
  // lane-local check is conservative-exact under __all. Rare path does the full reduce.
  const int ok = (t0 <= mrun0 + 8.f) && (t1 <= mrun1 + 8.f);
  if (!__all(ok)){
    float r0 = t0, r1 = t1;
    r0 = fmaxf(r0, __shfl_xor(r0, 16)); r0 = fmaxf(r0, __shfl_xor(r0, 32));
    r1 = fmaxf(r1, __shfl_xor(r1, 16)); r1 = fmaxf(r1, __shfl_xor(r1, 32));
    const float mn0 = fmaxf(mrun0, r0), mn1 = fmaxf(mrun1, r1);
    const float a0 = fast_exp2(mrun0 - mn0), a1 = fast_exp2(mrun1 - mn1);
    #pragma unroll
    for (int mf=0; mf<4; mf++){ o[mf][0] *= a0; o[mf][1] *= a1; }
    o4[0] *= a0; o4[1] *= a1;
    mrun0 = mn0; mrun1 = mn1;
  }

  // P = exp2(S - m), pack bf16, store P^T as [32q][64kv] (8B-chunk XOR swizzle)
  const int swp2 = 2*(li & 7);
  #pragma unroll
  for (int c=0;c<2;c++){
    const float mr = c ? mrun1 : mrun0;
    #pragma unroll
    for (int mf=0; mf<4; mf++){
      float p0 = fast_exp2(sa[mf][c][0] - mr);
      float p1 = fast_exp2(sa[mf][c][1] - mr);
      float p2 = fast_exp2(sa[mf][c][2] - mr);
      float p3 = fast_exp2(sa[mf][c][3] - mr);
      u32x2 pk = {pk_bf16(p0,p1), pk_bf16(p2,p3)};
      *(u32x2*)(pl + (c*16+li)*64 + (((4*mf+g) ^ swp2)*4)) = pk;
    }
  }

  // O^T(64d x 32q) += V^T * P^T ; row-sum via constant ones-row MFMA
  bf16x8 av[2][4];
  #pragma unroll
  for (int s=0; s<2; s++)
    #pragma unroll
    for (int mf=0; mf<4; mf++){
      const int row = mf*16 + li, sw = row & 7;
      av[s][mf] = *(const bf16x8*)(vtc + row*64 + (((4*s+g) ^ sw)*8));
    }
  __builtin_amdgcn_s_setprio(1);
  #pragma unroll
  for (int c=0;c<2;c++){
    #pragma unroll
    for (int s=0; s<2; s++){
      bf16x8 pb = *(const bf16x8*)(pl + (c*16+li)*64 + (((8*s+2*g) ^ swp2)*4));
      o4[c] = MFMA16(ones, pb, o4[c]);
      #pragma unroll
      for (int mf=0; mf<4; mf++)
        o[mf][c] = MFMA16(av[s][mf], pb, o[mf][c]);
    }
  }
  __builtin_amdgcn_s_setprio(0);
  __builtin_amdgcn_s_barrier();                            // B: done reading tile t
}

__global__ __launch_bounds__(256, 2) void k_attn(
    const uint16_t* __restrict__ qg, const uint16_t* __restrict__ kg,
    const uint16_t* __restrict__ vg, const float* __restrict__ biast,
    uint16_t* __restrict__ outp)
{
  __shared__ __align__(16) uint16_t kt[2][64*64];  // K tile [kv][d], 16B-chunk ^= row&7
  __shared__ __align__(16) uint16_t vt[2][64*64];  // V^T tile [d][kv], same swizzle
  __shared__ __align__(16) uint16_t pt[4][32*64];  // per-wave P^T [32q][64kv]
  const int tid = threadIdx.x;
  const int lane = tid & 63, w = tid >> 6;         // 4 waves
  const int g = lane >> 4, li = lane & 15;
  const int bh = blockIdx.y, h = bh & 15, b_ = bh >> 4;
  const int qb0 = blockIdx.x * 128;
  const int qw = qb0 + w*32;                       // wave's q base (32 rows)

  bf16x8 qf[2][2];
  #pragma unroll
  for (int c=0;c<2;c++){
    const uint16_t* qp = qg + ((size_t)bh*2048 + qw + c*16 + li)*64 + g*8;
    qf[c][0] = *(const bf16x8*)(qp);
    qf[c][1] = *(const bf16x8*)(qp + 32);
  }
  bf16x8 ones = (bf16x8)(short)0;                  // A-frag: row 0 = 1.0, rows 1-15 = 0
  if (li == 0){ const short v = (short)0x3F80; ones = (bf16x8){v,v,v,v,v,v,v,v}; }

  f32x4 o[4][2] = {};
  f32x4 o4[2] = {};
  float mrun0 = -__builtin_inff(), mrun1 = -__builtin_inff();

  const uint16_t* kbase = kg + (size_t)bh*(2048*64);
  const uint16_t* vbase = vg + (size_t)bh*(64*2048);
  const int srow = tid >> 3;                       // 0..31
  const int scg  = (tid & 7) ^ (srow & 7);
  const float* bb = biast + h*4096 + 2047 - qw;    // + kv - (c*16+li)
  uint16_t* pl = &pt[w][0];

  // prologue: stage tile 0, bias tile 0
  gload16(kbase + (size_t)srow*64 + scg*8,         &kt[0][tid*8]);
  gload16(kbase + (size_t)(srow+32)*64 + scg*8,    &kt[0][2048 + tid*8]);
  gload16(vbase + (size_t)srow*2048 + scg*8,       &vt[0][tid*8]);
  gload16(vbase + (size_t)(srow+32)*2048 + scg*8,  &vt[0][2048 + tid*8]);
  f32x4 bvA[2][4], bvB[2][4];
  #pragma unroll
  for (int c=0;c<2;c++)
    #pragma unroll
    for (int mf=0;mf<4;mf++)
      bvA[c][mf] = *(const f32x4u*)(bb + mf*16 + g*4 - c*16 - li);

  for (int tt = 0; tt < 32; tt += 2){
    attn_tile(tt,   false,    tid, g, li, srow, scg, kbase, vbase, bb,
              &kt[0][0], &kt[1][0], &vt[0][0], &vt[1][0], pl,
              qf, ones, o, o4, mrun0, mrun1, bvA, bvB);
    attn_tile(tt+1, tt == 30, tid, g, li, srow, scg, kbase, vbase, bb,
              &kt[1][0], &kt[0][0], &vt[1][0], &vt[0][0], pl,
              qf, ones, o, o4, mrun0, mrun1, bvB, bvA);
  }

  // row sums live in o4[c] reg 0 of lane-group g=0; broadcast to all g
  const float ls0 = __shfl(o4[0][0], li);
  const float ls1 = __shfl(o4[1][0], li);
  const float inv0 = 1.0f / ls0, inv1 = 1.0f / ls1;
  #pragma unroll
  for (int c=0;c<2;c++){
    const float inv = c ? inv1 : inv0;
    const size_t token = (size_t)b_*2048 + qw + c*16 + li;
    #pragma unroll
    for (int mf=0; mf<4; mf++){
      u32x2 pk = {pk_bf16(o[mf][c][0]*inv, o[mf][c][1]*inv),
                  pk_bf16(o[mf][c][2]*inv, o[mf][c][3]*inv)};
      *(u32x2*)(outp + token*1024 + h*64 + mf*16 + g*4) = pk;
    }
  }
}

// ---------- launch ----------
extern "C" void kernel_launch(void* const* d_in, const int* in_sizes, int n_in,
                              void* d_out, int out_size, void* d_ws, size_t ws_size,
                              hipStream_t stream)
{
  const float* x      = (const float*)d_in[0];
  const float* qkv_w  = (const float*)d_in[1];
  const float* qkv_b  = (const float*)d_in[2];
  const float* proj_w = (const float*)d_in[3];
  const float* proj_b = (const float*)d_in[4];
  const float* btab   = (const float*)d_in[5];
  float* out = (float*)d_out;

  char* p = (char*)d_ws;
  uint16_t* x_bf    = (uint16_t*)(p);
  uint16_t* qkv_wt  = (uint16_t*)(p + 8388608);
  uint16_t* proj_wt = (uint16_t*)(p + 14680064);
  uint16_t* q_buf   = (uint16_t*)(p + 16777216);   // (b,h,l,d) bf16, prescaled
  uint16_t* k_buf   = (uint16_t*)(p + 25165824);   // (b,h,l,d) bf16
  uint16_t* vt_buf  = (uint16_t*)(p + 33554432);   // (b,h,d,l) bf16
  uint16_t* ao_buf  = (uint16_t*)(p + 41943040);   // attn out (tokens x 1024) bf16
  float*    bias_t  = (float*)   (p + 50331648);   // 16 x 4096 f32, *log2e

  k_cvt  <<<dim3(4096),  dim3(256), 0, stream>>>(x, x_bf);
  k_tcvt <<<dim3(48,16), dim3(256), 0, stream>>>(qkv_w,  qkv_wt,  1024, 3072);
  k_tcvt <<<dim3(16,16), dim3(256), 0, stream>>>(proj_w, proj_wt, 1024, 1024);
  k_biast<<<dim3(256),   dim3(256), 0, stream>>>(btab, bias_t);

  k_gemm<0><<<dim3(24,32), dim3(256), 0, stream>>>(x_bf, qkv_wt, qkv_b, q_buf, k_buf, vt_buf, nullptr);
  k_attn   <<<dim3(16,32), dim3(256), 0, stream>>>(q_buf, k_buf, vt_buf, bias_t, ao_buf);
  k_gemm<1><<<dim3(8,32),  dim3(256), 0, stream>>>(ao_buf, proj_wt, proj_b, nullptr, nullptr, nullptr, out);
}